// Round 1
// baseline (5209.993 us; speedup 1.0000x reference)
//
#include <hip/hip_runtime.h>
#include <cstddef>
#include <cstdint>

// ---------------------------------------------------------------------------
// AttentionGoalState — f32 baseline.
//
// Key simplification (mathematically exact up to fp rounding):
//   attn = softmax(KQ, axis=2); Vn = V * attn.sum(axis=2)  ==>  rowsums == 1
//   so Vn == V, and K/Q GEMMs + S^2 softmax are skipped entirely.
//
// Everything is kept in pixel-major [P, C] layout so all convs become GEMMs:
//   conv1x1        -> [P,Cin] x [Cin,Cout]
//   convT 2x2 s2   -> 4 GEMMs with output-row remap (non-overlapping taps)
//   conv3d 3x3x3   -> direct kernel with LDS-staged weights
// ---------------------------------------------------------------------------

static constexpr int B_ = 8, TC = 6, TF = 4, DIN = 1024, DFF = 512, DOUT = 128;
static constexpr int HWP = 144;                  // 12*12
static constexpr int P_CTX = B_ * TC * HWP;      // 6912
static constexpr int NF = B_ * TF;               // 32
static constexpr int P_FRM = NF * HWP;           // 4608
static constexpr int P_H1 = NF * 24 * 24;        // 18432
static constexpr int P_H2 = NF * 48 * 48;        // 73728
static constexpr int S2 = 48 * 48;               // 2304

// workspace offsets in floats (phase-aliased; peak ~104 MB)
static constexpr size_t OFF_X0    = 0;
static constexpr size_t OFF_X1    = OFF_X0 + (size_t)P_CTX * DIN;    // 7077888
static constexpr size_t OFF_VN    = OFF_X1 + (size_t)P_CTX * DIN;    // 14155776 (alias: conv3d Wt)
static constexpr size_t OFF_WT1   = OFF_VN + (size_t)P_CTX * DFF;    // 17694720 (alias: G)
static constexpr size_t OFF_WT2   = OFF_WT1 + (size_t)DFF * DIN;     // 18219008
static constexpr size_t OFF_STATS = OFF_WT2 + (size_t)DFF * DIN;     // 18743296
static constexpr size_t OFF_HP2   = 0;                                // phase C
static constexpr size_t OFF_HP1   = OFF_HP2 + (size_t)P_H2 * DOUT;   // 9437184
static constexpr size_t OFF_F0    = OFF_HP1 + (size_t)P_H1 * DFF;    // 18874368
static constexpr size_t OFF_W1T   = OFF_F0 + (size_t)P_FRM * DIN;    // 23592960
static constexpr size_t OFF_W2T   = OFF_W1T + (size_t)4 * DIN * DFF; // 25690112

// --------------------------- helpers ---------------------------------------

__global__ __launch_bounds__(256) void zero_f32(float* p, int n) {
    int i = blockIdx.x * 256 + threadIdx.x;
    if (i < n) p[i] = 0.f;
}

// [F][C][HW] -> [F*HW][C]  (tiled transpose, both sides coalesced)
__global__ __launch_bounds__(256) void transpose_cm_pm(const float* __restrict__ in,
                                                       float* __restrict__ out,
                                                       int C, int HW) {
    __shared__ float T[64][17];
    int tx = threadIdx.x, ty = threadIdx.y;
    int f = blockIdx.z, hw0 = blockIdx.x * 16, c0 = blockIdx.y * 64;
#pragma unroll
    for (int i = 0; i < 4; ++i)
        T[ty + 16 * i][tx] = in[((size_t)f * C + c0 + ty + 16 * i) * HW + hw0 + tx];
    __syncthreads();
#pragma unroll
    for (int i = 0; i < 4; ++i)
        out[((size_t)f * HW + hw0 + ty) * C + c0 + tx + 16 * i] = T[tx + 16 * i][ty];
}

// out[c*O + o] = in[o*C + c]
__global__ __launch_bounds__(256) void wt_oc(const float* __restrict__ in,
                                             float* __restrict__ out, int O, int C) {
    int idx = blockIdx.x * 256 + threadIdx.x;
    if (idx >= O * C) return;
    int o = idx % O, c = idx / O;
    out[idx] = in[(size_t)o * C + c];
}

// tp_w [128][1024][27] -> Tw [27][1024][128]
__global__ __launch_bounds__(256) void tw_conv_t(const float* __restrict__ tp,
                                                 float* __restrict__ Tw) {
    int idx = blockIdx.x * 256 + threadIdx.x;
    if (idx >= 27 * 1024 * 128) return;
    int o = idx & 127, r = idx >> 7;
    int c = r & 1023, tap = r >> 10;
    Tw[idx] = tp[((size_t)o * 1024 + c) * 27 + tap];
}

// up_w [Cin][Cout][2][2] -> [4][Cin][Cout]
__global__ __launch_bounds__(256) void up_w_t(const float* __restrict__ win,
                                              float* __restrict__ wout, int Cin, int Cout) {
    int idx = blockIdx.x * 256 + threadIdx.x;
    if (idx >= 4 * Cin * Cout) return;
    int o = idx % Cout, r = idx / Cout;
    int c = r % Cin, d = r / Cin;
    wout[idx] = win[((size_t)c * Cout + o) * 4 + d];
}

// --------------------------- GEMM ------------------------------------------
// C[M,N] = op(A[M,K] x B[K,N] + bias), optional relu / residual / out-row remap.
// BM=BN=128, BK=16, 256 threads, 8x8 per thread. All dims divide exactly here.
template <int RELU, int RESID, int REMAP>
__global__ __launch_bounds__(256) void gemm_f32(
    const float* __restrict__ A, const float* __restrict__ B,
    const float* __restrict__ bias, const float* __restrict__ resid,
    float* __restrict__ C, int M, int N, int K,
    int inW, int inHW, int outW, int dh, int dw, int outSPP) {
    __shared__ float As[16][132];
    __shared__ float Bs[16][132];
    int tid = threadIdx.x;
    int tx = tid & 15, ty = tid >> 4;
    int m0 = blockIdx.y * 128, n0 = blockIdx.x * 128;
    float acc[8][8] = {};

    for (int k0 = 0; k0 < K; k0 += 16) {
#pragma unroll
        for (int i = 0; i < 8; ++i) {
            int e = tid + i * 256;
            int am = e >> 4, ak = e & 15;
            As[ak][am] = A[(size_t)(m0 + am) * K + k0 + ak];
        }
#pragma unroll
        for (int i = 0; i < 8; ++i) {
            int e = tid + i * 256;
            int bk = e >> 7, bn = e & 127;
            Bs[bk][bn] = B[(size_t)(k0 + bk) * N + n0 + bn];
        }
        __syncthreads();
#pragma unroll
        for (int k = 0; k < 16; ++k) {
            float a[8], b[8];
#pragma unroll
            for (int i = 0; i < 8; ++i) a[i] = As[k][ty + 16 * i];
#pragma unroll
            for (int j = 0; j < 8; ++j) b[j] = Bs[k][tx + 16 * j];
#pragma unroll
            for (int i = 0; i < 8; ++i)
#pragma unroll
                for (int j = 0; j < 8; ++j) acc[i][j] += a[i] * b[j];
        }
        __syncthreads();
    }

#pragma unroll
    for (int i = 0; i < 8; ++i) {
        int m = m0 + ty + 16 * i;
        int orow;
        if (REMAP) {
            int ni = m / inHW;
            int rem = m - ni * inHW;
            int h = rem / inW, w = rem - h * inW;
            orow = ni * outSPP + (2 * h + dh) * outW + (2 * w + dw);
        } else {
            orow = m;
        }
        const float* rrow = RESID ? resid + (size_t)m * N : nullptr;
        float* crow = C + (size_t)orow * N;
#pragma unroll
        for (int j = 0; j < 8; ++j) {
            int n = n0 + tx + 16 * j;
            float v = acc[i][j] + bias[n];
            if (RELU) v = fmaxf(v, 0.f);
            if (RESID) v += rrow[n];
            crow[n] = v;
        }
    }
}

// --------------------------- BatchNorm --------------------------------------

__global__ __launch_bounds__(256) void bn_stats(const float* __restrict__ Y,
                                                float* __restrict__ st) {
    int tid = threadIdx.x;
    int p0 = blockIdx.x * 64;
    float s[4] = {0, 0, 0, 0}, q[4] = {0, 0, 0, 0};
    for (int pp = 0; pp < 64; ++pp) {
        const float* row = Y + (size_t)(p0 + pp) * 1024 + tid;
#pragma unroll
        for (int j = 0; j < 4; ++j) {
            float v = row[256 * j];
            s[j] += v;
            q[j] += v * v;
        }
    }
#pragma unroll
    for (int j = 0; j < 4; ++j) {
        atomicAdd(&st[tid + 256 * j], s[j]);
        atomicAdd(&st[1024 + tid + 256 * j], q[j]);
    }
}

__global__ __launch_bounds__(256) void bn_final(float* __restrict__ st,
                                                const float* __restrict__ gamma,
                                                const float* __restrict__ beta) {
    int c = blockIdx.x * 256 + threadIdx.x;
    if (c >= 1024) return;
    const float invn = 1.f / 6912.f;
    float mean = st[c] * invn;
    float var = st[1024 + c] * invn - mean * mean;
    float sc = gamma[c] * rsqrtf(var + 1e-5f);
    st[2048 + c] = sc;
    st[3072 + c] = beta[c] - mean * sc;
}

__global__ __launch_bounds__(256) void bn_apply(float* __restrict__ Y,
                                                const float* __restrict__ st) {
    const float* scale = st + 2048;
    const float* shift = st + 3072;
    int idx = blockIdx.x * 256 + threadIdx.x;  // over P_CTX*1024/4
    float4* Y4 = (float4*)Y;
    int c0 = (idx & 255) << 2;
    float4 v = Y4[idx];
    v.x = v.x * scale[c0 + 0] + shift[c0 + 0];
    v.y = v.y * scale[c0 + 1] + shift[c0 + 1];
    v.z = v.z * scale[c0 + 2] + shift[c0 + 2];
    v.w = v.w * scale[c0 + 3] + shift[c0 + 3];
    Y4[idx] = v;
}

// --------------------------- Conv3d 3x3x3 (VALID) ---------------------------
// X pixel-major [6912][1024]; Tw [27][1024][128]; G [3200][128] (raw sums).
__global__ __launch_bounds__(256) void conv3d_tp(const float* __restrict__ X,
                                                 const float* __restrict__ Tw,
                                                 float* __restrict__ G) {
    __shared__ float Ws[64][128];
    int tid = threadIdx.x;
    int o = tid & 127, pg = tid >> 7;
    int pos0 = blockIdx.x * 8;
    int pixbase[4];
#pragma unroll
    for (int j = 0; j < 4; ++j) {
        int pos = pos0 + pg + 2 * j;
        int w = pos % 10;
        int r = pos / 10;
        int h = r % 10;
        r /= 10;
        int t = r & 3, b = r >> 2;
        pixbase[j] = ((b * 6 + t) * 12 + h) * 12 + w;
    }
    float acc[4] = {0, 0, 0, 0};
    for (int tap = 0; tap < 27; ++tap) {
        int dt = tap / 9, rr = tap - dt * 9;
        int doff = dt * 144 + (rr / 3) * 12 + (rr % 3);
        const float* twt = Tw + (size_t)tap * 1024 * 128;
        for (int c0 = 0; c0 < 1024; c0 += 64) {
            __syncthreads();
#pragma unroll
            for (int i = 0; i < 32; ++i) {
                int e = tid + i * 256;
                Ws[e >> 7][e & 127] = twt[(size_t)(c0 + (e >> 7)) * 128 + (e & 127)];
            }
            __syncthreads();
            const float* xp0 = X + (size_t)(pixbase[0] + doff) * 1024 + c0;
            const float* xp1 = X + (size_t)(pixbase[1] + doff) * 1024 + c0;
            const float* xp2 = X + (size_t)(pixbase[2] + doff) * 1024 + c0;
            const float* xp3 = X + (size_t)(pixbase[3] + doff) * 1024 + c0;
#pragma unroll
            for (int q = 0; q < 16; ++q) {
                float w0 = Ws[q * 4 + 0][o], w1 = Ws[q * 4 + 1][o];
                float w2 = Ws[q * 4 + 2][o], w3 = Ws[q * 4 + 3][o];
                float4 x0 = *(const float4*)(xp0 + q * 4);
                float4 x1 = *(const float4*)(xp1 + q * 4);
                float4 x2 = *(const float4*)(xp2 + q * 4);
                float4 x3 = *(const float4*)(xp3 + q * 4);
                acc[0] += x0.x * w0 + x0.y * w1 + x0.z * w2 + x0.w * w3;
                acc[1] += x1.x * w0 + x1.y * w1 + x1.z * w2 + x1.w * w3;
                acc[2] += x2.x * w0 + x2.y * w1 + x2.z * w2 + x2.w * w3;
                acc[3] += x3.x * w0 + x3.y * w1 + x3.z * w2 + x3.w * w3;
            }
        }
    }
#pragma unroll
    for (int j = 0; j < 4; ++j)
        G[(size_t)(pos0 + pg + 2 * j) * 128 + o] = acc[j];
}

// relu(G + bias) mean over 400 positions -> goal_embed [8][128] (front of d_out)
__global__ __launch_bounds__(128) void goal_reduce(const float* __restrict__ G,
                                                   const float* __restrict__ bias,
                                                   float* __restrict__ out) {
    int b = blockIdx.x, o = threadIdx.x;
    float bo = bias[o];
    float s = 0.f;
    for (int i = 0; i < 400; ++i)
        s += fmaxf(G[(size_t)(b * 400 + i) * 128 + o] + bo, 0.f);
    out[b * 128 + o] = s * (1.f / 400.f);
}

// --------------------------- final goal/state attention ----------------------
// Hp2 [32*2304][128] pixel-major == state_embed[n, d, s] transposed.
// goal_rep[n] = goal_embed[n % 8] (faithful to torch .repeat tiling).
__global__ __launch_bounds__(256) void attn_final(const float* __restrict__ Hp2,
                                                  float* __restrict__ out) {
    __shared__ __align__(16) float sGoal[128];
    __shared__ float sAttn[S2];
    __shared__ float red[256];
    int n = blockIdx.x, tid = threadIdx.x;
    if (tid < 128) sGoal[tid] = out[(n & 7) * 128 + tid];
    __syncthreads();
    const float scale = 0.0883883476483184f;  // 1/sqrt(128)
    float lmax = -3.4e38f;
    for (int s = tid; s < S2; s += 256) {
        const float4* row = (const float4*)(Hp2 + (size_t)(n * S2 + s) * 128);
        const float4* g4 = (const float4*)sGoal;
        float a = 0.f;
#pragma unroll
        for (int q = 0; q < 32; ++q) {
            float4 v = row[q], g = g4[q];
            a += v.x * g.x + v.y * g.y + v.z * g.z + v.w * g.w;
        }
        a *= scale;
        sAttn[s] = a;
        lmax = fmaxf(lmax, a);
    }
    red[tid] = lmax;
    __syncthreads();
    for (int off = 128; off > 0; off >>= 1) {
        if (tid < off) red[tid] = fmaxf(red[tid], red[tid + off]);
        __syncthreads();
    }
    float m = red[0];
    __syncthreads();
    float lsum = 0.f;
    for (int s = tid; s < S2; s += 256) {
        float e = expf(sAttn[s] - m);
        sAttn[s] = e;
        lsum += e;
    }
    red[tid] = lsum;
    __syncthreads();
    for (int off = 128; off > 0; off >>= 1) {
        if (tid < off) red[tid] += red[tid + off];
        __syncthreads();
    }
    float inv = 1.f / red[0];
    if (tid < 128) {
        int d = tid;
        float freq = expf(-(float)(d & ~1) * (9.210340371976184f / 128.f));
        bool odd = d & 1;
        float acc = 0.f;
        for (int s = 0; s < S2; ++s) {
            float ang = (float)s * freq;
            float pe = odd ? cosf(ang) : sinf(ang);
            acc += sAttn[s] * (Hp2[(size_t)(n * S2 + s) * 128 + d] + pe);
        }
        out[1024 + n * 128 + d] = acc * inv;
    }
}

// --------------------------- launch ------------------------------------------

extern "C" void kernel_launch(void* const* d_in, const int* in_sizes, int n_in,
                              void* d_out, int out_size, void* d_ws, size_t ws_size,
                              hipStream_t stream) {
    const float* context = (const float*)d_in[0];
    const float* frame = (const float*)d_in[1];
    // d_in[2..5]: nl_Kw/Kb/Qw/Qb — unused (softmax rowsum == 1, see header)
    const float* Vw = (const float*)d_in[6];
    const float* Vb = (const float*)d_in[7];
    const float* Ow = (const float*)d_in[8];
    const float* Ob = (const float*)d_in[9];
    const float* gamma = (const float*)d_in[10];
    const float* beta = (const float*)d_in[11];
    const float* tpw = (const float*)d_in[12];
    const float* tpb = (const float*)d_in[13];
    const float* u1w = (const float*)d_in[14];
    const float* u1b = (const float*)d_in[15];
    const float* u2w = (const float*)d_in[16];
    const float* u2b = (const float*)d_in[17];
    float* ws = (float*)d_ws;
    float* out = (float*)d_out;

    float* X0 = ws + OFF_X0;
    float* X1 = ws + OFF_X1;
    float* VN = ws + OFF_VN;
    float* WT1 = ws + OFF_WT1;
    float* WT2 = ws + OFF_WT2;
    float* ST = ws + OFF_STATS;
    float* TWT = ws + OFF_VN;   // alias (VN dead by then)
    float* G = ws + OFF_WT1;    // alias (WT1 dead by then)
    float* HP2 = ws + OFF_HP2;  // alias over X0 region (phase C)
    float* HP1 = ws + OFF_HP1;
    float* F0 = ws + OFF_F0;
    float* W1T = ws + OFF_W1T;
    float* W2T = ws + OFF_W2T;

    // context [8][6][1024][144] -> X0 [6912][1024]
    transpose_cm_pm<<<dim3(HWP / 16, DIN / 64, B_ * TC), dim3(16, 16), 0, stream>>>(
        context, X0, DIN, HWP);

    float* Xin = X0;
    float* Y = X1;
    for (int l = 0; l < 2; ++l) {
        wt_oc<<<(DFF * DIN + 255) / 256, 256, 0, stream>>>(Vw + (size_t)l * DFF * DIN, WT1, DFF, DIN);
        wt_oc<<<(DIN * DFF + 255) / 256, 256, 0, stream>>>(Ow + (size_t)l * DIN * DFF, WT2, DIN, DFF);
        // Vn = relu(X*Vw^T + Vb)
        gemm_f32<1, 0, 0><<<dim3(DFF / 128, P_CTX / 128), 256, 0, stream>>>(
            Xin, WT1, Vb + l * DFF, nullptr, VN, P_CTX, DFF, DIN, 0, 0, 0, 0, 0, 0);
        // Y = X + relu(Vn*Ow^T + Ob)
        gemm_f32<1, 1, 0><<<dim3(DIN / 128, P_CTX / 128), 256, 0, stream>>>(
            VN, WT2, Ob + l * DIN, Xin, Y, P_CTX, DIN, DFF, 0, 0, 0, 0, 0, 0);
        // BatchNorm (training-mode batch stats) in place on Y
        zero_f32<<<8, 256, 0, stream>>>(ST, 2048);
        bn_stats<<<P_CTX / 64, 256, 0, stream>>>(Y, ST);
        bn_final<<<4, 256, 0, stream>>>(ST, gamma + l * DIN, beta + l * DIN);
        bn_apply<<<(P_CTX * DIN / 4) / 256, 256, 0, stream>>>(Y, ST);
        float* t = Xin;
        Xin = Y;
        Y = t;
    }
    // Xin == X0 now (final non-local output)

    // temporal pool -> goal_embed
    tw_conv_t<<<(27 * DIN * DOUT + 255) / 256, 256, 0, stream>>>(tpw, TWT);
    conv3d_tp<<<400, 256, 0, stream>>>(Xin, TWT, G);
    goal_reduce<<<8, 128, 0, stream>>>(G, tpb, out);

    // frame upsample path
    transpose_cm_pm<<<dim3(HWP / 16, DIN / 64, NF), dim3(16, 16), 0, stream>>>(
        frame, F0, DIN, HWP);
    up_w_t<<<(4 * DIN * DFF + 255) / 256, 256, 0, stream>>>(u1w, W1T, DIN, DFF);
    up_w_t<<<(4 * DFF * DOUT + 255) / 256, 256, 0, stream>>>(u2w, W2T, DFF, DOUT);
    for (int d = 0; d < 4; ++d) {
        int dh = d >> 1, dw = d & 1;
        gemm_f32<1, 0, 1><<<dim3(DFF / 128, P_FRM / 128), 256, 0, stream>>>(
            F0, W1T + (size_t)d * DIN * DFF, u1b, nullptr, HP1, P_FRM, DFF, DIN,
            12, 144, 24, dh, dw, 576);
    }
    for (int d = 0; d < 4; ++d) {
        int dh = d >> 1, dw = d & 1;
        gemm_f32<0, 0, 1><<<dim3(DOUT / 128, P_H1 / 128), 256, 0, stream>>>(
            HP1, W2T + (size_t)d * DFF * DOUT, u2b, nullptr, HP2, P_H1, DOUT, DFF,
            24, 576, 48, dh, dw, 2304);
    }

    // final goal/state attention (+ positional encoding computed on the fly)
    attn_final<<<NF, 256, 0, stream>>>(HP2, out);
}

// Round 2
// 2997.720 us; speedup vs baseline: 1.7380x; 1.7380x over previous
//
#include <hip/hip_runtime.h>
#include <cstddef>
#include <cstdint>

// ---------------------------------------------------------------------------
// AttentionGoalState — f32, round 2: conv3d restructured as split-K GEMM.
//
// Key simplification (mathematically exact up to fp rounding):
//   attn = softmax(KQ, axis=2); Vn = V * attn.sum(axis=2)  ==>  rowsums == 1
//   so Vn == V, and K/Q GEMMs + S^2 softmax are skipped entirely.
//
// Everything is kept in pixel-major [P, C] layout so all convs become GEMMs:
//   conv1x1        -> [P,Cin] x [Cin,Cout]
//   convT 2x2 s2   -> 4 GEMMs with output-row remap (non-overlapping taps)
//   conv3d 3x3x3   -> split-K GEMM: 27 taps x 25 M-blocks, partials + reduce
// ---------------------------------------------------------------------------

static constexpr int B_ = 8, TC = 6, TF = 4, DIN = 1024, DFF = 512, DOUT = 128;
static constexpr int HWP = 144;                  // 12*12
static constexpr int P_CTX = B_ * TC * HWP;      // 6912
static constexpr int NF = B_ * TF;               // 32
static constexpr int P_FRM = NF * HWP;           // 4608
static constexpr int P_H1 = NF * 24 * 24;        // 18432
static constexpr int P_H2 = NF * 48 * 48;        // 73728
static constexpr int S2 = 48 * 48;               // 2304
static constexpr int NPOS = 3200;                // 8*4*10*10 conv3d outputs

// workspace offsets in floats (phase-aliased; peak ~104 MB)
static constexpr size_t OFF_X0    = 0;
static constexpr size_t OFF_X1    = OFF_X0 + (size_t)P_CTX * DIN;    // 7077888
static constexpr size_t OFF_VN    = OFF_X1 + (size_t)P_CTX * DIN;    // 14155776
static constexpr size_t OFF_WT1   = OFF_VN + (size_t)P_CTX * DFF;    // 17694720
static constexpr size_t OFF_WT2   = OFF_WT1 + (size_t)DFF * DIN;     // 18219008
static constexpr size_t OFF_STATS = OFF_WT2 + (size_t)DFF * DIN;     // 18743296
// conv3d phase (X1/VN/WT*/STATS dead; X0 still live):
static constexpr size_t OFF_GP    = OFF_X1;                           // 27*3200*128 = 11059200
static constexpr size_t OFF_TWT   = OFF_GP + (size_t)27 * NPOS * DOUT;   // 18137088
static constexpr size_t OFF_R     = OFF_TWT + (size_t)27 * DIN * DOUT;   // 21676032
// upsample phase (everything above dead):
static constexpr size_t OFF_HP2   = 0;
static constexpr size_t OFF_HP1   = OFF_HP2 + (size_t)P_H2 * DOUT;   // 9437184
static constexpr size_t OFF_F0    = OFF_HP1 + (size_t)P_H1 * DFF;    // 18874368
static constexpr size_t OFF_W1T   = OFF_F0 + (size_t)P_FRM * DIN;    // 23592960
static constexpr size_t OFF_W2T   = OFF_W1T + (size_t)4 * DIN * DFF; // 25690112

// --------------------------- helpers ---------------------------------------

__global__ __launch_bounds__(256) void zero_f32(float* p, int n) {
    int i = blockIdx.x * 256 + threadIdx.x;
    if (i < n) p[i] = 0.f;
}

// [F][C][HW] -> [F*HW][C]  (tiled transpose, both sides coalesced)
__global__ __launch_bounds__(256) void transpose_cm_pm(const float* __restrict__ in,
                                                       float* __restrict__ out,
                                                       int C, int HW) {
    __shared__ float T[64][17];
    int tx = threadIdx.x, ty = threadIdx.y;
    int f = blockIdx.z, hw0 = blockIdx.x * 16, c0 = blockIdx.y * 64;
#pragma unroll
    for (int i = 0; i < 4; ++i)
        T[ty + 16 * i][tx] = in[((size_t)f * C + c0 + ty + 16 * i) * HW + hw0 + tx];
    __syncthreads();
#pragma unroll
    for (int i = 0; i < 4; ++i)
        out[((size_t)f * HW + hw0 + ty) * C + c0 + tx + 16 * i] = T[tx + 16 * i][ty];
}

// out[c*O + o] = in[o*C + c]
__global__ __launch_bounds__(256) void wt_oc(const float* __restrict__ in,
                                             float* __restrict__ out, int O, int C) {
    int idx = blockIdx.x * 256 + threadIdx.x;
    if (idx >= O * C) return;
    int o = idx % O, c = idx / O;
    out[idx] = in[(size_t)o * C + c];
}

// tp_w [128][1024][27] -> Tw [27][1024][128]
__global__ __launch_bounds__(256) void tw_conv_t(const float* __restrict__ tp,
                                                 float* __restrict__ Tw) {
    int idx = blockIdx.x * 256 + threadIdx.x;
    if (idx >= 27 * 1024 * 128) return;
    int o = idx & 127, r = idx >> 7;
    int c = r & 1023, tap = r >> 10;
    Tw[idx] = tp[((size_t)o * 1024 + c) * 27 + tap];
}

// up_w [Cin][Cout][2][2] -> [4][Cin][Cout]
__global__ __launch_bounds__(256) void up_w_t(const float* __restrict__ win,
                                              float* __restrict__ wout, int Cin, int Cout) {
    int idx = blockIdx.x * 256 + threadIdx.x;
    if (idx >= 4 * Cin * Cout) return;
    int o = idx % Cout, r = idx / Cout;
    int c = r % Cin, d = r / Cin;
    wout[idx] = win[((size_t)c * Cout + o) * 4 + d];
}

// --------------------------- GEMM ------------------------------------------
// C[M,N] = op(A[M,K] x B[K,N] + bias), optional relu / residual / out-row remap.
// BM=BN=128, BK=16, 256 threads, 8x8 per thread. All dims divide exactly here.
template <int RELU, int RESID, int REMAP>
__global__ __launch_bounds__(256) void gemm_f32(
    const float* __restrict__ A, const float* __restrict__ B,
    const float* __restrict__ bias, const float* __restrict__ resid,
    float* __restrict__ C, int M, int N, int K,
    int inW, int inHW, int outW, int dh, int dw, int outSPP) {
    __shared__ float As[16][132];
    __shared__ float Bs[16][132];
    int tid = threadIdx.x;
    int tx = tid & 15, ty = tid >> 4;
    int m0 = blockIdx.y * 128, n0 = blockIdx.x * 128;
    float acc[8][8] = {};

    for (int k0 = 0; k0 < K; k0 += 16) {
#pragma unroll
        for (int i = 0; i < 8; ++i) {
            int e = tid + i * 256;
            int am = e >> 4, ak = e & 15;
            As[ak][am] = A[(size_t)(m0 + am) * K + k0 + ak];
        }
#pragma unroll
        for (int i = 0; i < 8; ++i) {
            int e = tid + i * 256;
            int bk = e >> 7, bn = e & 127;
            Bs[bk][bn] = B[(size_t)(k0 + bk) * N + n0 + bn];
        }
        __syncthreads();
#pragma unroll
        for (int k = 0; k < 16; ++k) {
            float a[8], b[8];
#pragma unroll
            for (int i = 0; i < 8; ++i) a[i] = As[k][ty + 16 * i];
#pragma unroll
            for (int j = 0; j < 8; ++j) b[j] = Bs[k][tx + 16 * j];
#pragma unroll
            for (int i = 0; i < 8; ++i)
#pragma unroll
                for (int j = 0; j < 8; ++j) acc[i][j] += a[i] * b[j];
        }
        __syncthreads();
    }

#pragma unroll
    for (int i = 0; i < 8; ++i) {
        int m = m0 + ty + 16 * i;
        int orow;
        if (REMAP) {
            int ni = m / inHW;
            int rem = m - ni * inHW;
            int h = rem / inW, w = rem - h * inW;
            orow = ni * outSPP + (2 * h + dh) * outW + (2 * w + dw);
        } else {
            orow = m;
        }
        const float* rrow = RESID ? resid + (size_t)m * N : nullptr;
        float* crow = C + (size_t)orow * N;
#pragma unroll
        for (int j = 0; j < 8; ++j) {
            int n = n0 + tx + 16 * j;
            float v = acc[i][j] + bias[n];
            if (RELU) v = fmaxf(v, 0.f);
            if (RESID) v += rrow[n];
            crow[n] = v;
        }
    }
}

// ---------------- conv3d as split-K GEMM ------------------------------------
// X pixel-major [6912][1024]; Tw [27][1024][128].
// grid (27 taps, 25 M-blocks); each block: [128 pos,1024ch] x [1024,128] f32.
// Partials to Gp[tap][3200][128].
__global__ __launch_bounds__(256) void gemm_conv3(const float* __restrict__ X,
                                                  const float* __restrict__ Tw,
                                                  float* __restrict__ Gp) {
    __shared__ float As[16][132];
    __shared__ float Bs[16][132];
    __shared__ int sPix[128];
    int tid = threadIdx.x;
    int tap = blockIdx.x;
    int m0 = blockIdx.y * 128;
    int dt = tap / 9, rr = tap - dt * 9;
    int doff = dt * 144 + (rr / 3) * 12 + (rr % 3);
    if (tid < 128) {
        int pos = m0 + tid;
        int w = pos % 10;
        int r = pos / 10;
        int h = r % 10;
        r /= 10;
        int t = r & 3, b = r >> 2;
        sPix[tid] = ((b * 6 + t) * 12 + h) * 12 + w + doff;  // input row
    }
    __syncthreads();
    int tx = tid & 15, ty = tid >> 4;
    size_t rowb[8];
#pragma unroll
    for (int i = 0; i < 8; ++i) rowb[i] = (size_t)sPix[(tid >> 4) + 16 * i] * 1024;
    const float* Bw = Tw + (size_t)tap * 1024 * 128;
    float acc[8][8] = {};

    for (int k0 = 0; k0 < 1024; k0 += 16) {
#pragma unroll
        for (int i = 0; i < 8; ++i) {
            int am = (tid >> 4) + 16 * i, ak = tid & 15;
            As[ak][am] = X[rowb[i] + k0 + ak];
        }
#pragma unroll
        for (int i = 0; i < 8; ++i) {
            int e = tid + i * 256;
            int bk = e >> 7, bn = e & 127;
            Bs[bk][bn] = Bw[(size_t)(k0 + bk) * 128 + bn];
        }
        __syncthreads();
#pragma unroll
        for (int k = 0; k < 16; ++k) {
            float a[8], b[8];
#pragma unroll
            for (int i = 0; i < 8; ++i) a[i] = As[k][ty + 16 * i];
#pragma unroll
            for (int j = 0; j < 8; ++j) b[j] = Bs[k][tx + 16 * j];
#pragma unroll
            for (int i = 0; i < 8; ++i)
#pragma unroll
                for (int j = 0; j < 8; ++j) acc[i][j] += a[i] * b[j];
        }
        __syncthreads();
    }

    float* Go = Gp + (size_t)tap * NPOS * 128 + (size_t)m0 * 128;
#pragma unroll
    for (int i = 0; i < 8; ++i)
#pragma unroll
        for (int j = 0; j < 8; ++j)
            Go[(size_t)(ty + 16 * i) * 128 + tx + 16 * j] = acc[i][j];
}

// sum 27 tap-partials, + bias, relu -> R[3200][128]
__global__ __launch_bounds__(256) void conv3_reduce(const float* __restrict__ Gp,
                                                    const float* __restrict__ bias,
                                                    float* __restrict__ R) {
    int idx = blockIdx.x * 256 + threadIdx.x;  // 3200*128
    float s = 0.f;
    for (int tap = 0; tap < 27; ++tap) s += Gp[(size_t)tap * (NPOS * 128) + idx];
    R[idx] = fmaxf(s + bias[idx & 127], 0.f);
}

// mean over 400 positions -> goal_embed [8][128] (front of d_out)
__global__ __launch_bounds__(128) void goal_reduce(const float* __restrict__ R,
                                                   const float* __restrict__ bias,
                                                   float* __restrict__ out) {
    int b = blockIdx.x, o = threadIdx.x;
    float s = 0.f;
    for (int i = 0; i < 400; ++i) s += R[(size_t)(b * 400 + i) * 128 + o];
    out[b * 128 + o] = s * (1.f / 400.f);
}

// --------------------------- BatchNorm --------------------------------------

__global__ __launch_bounds__(256) void bn_stats(const float* __restrict__ Y,
                                                float* __restrict__ st) {
    int tid = threadIdx.x;
    int p0 = blockIdx.x * 64;
    float s[4] = {0, 0, 0, 0}, q[4] = {0, 0, 0, 0};
    for (int pp = 0; pp < 64; ++pp) {
        const float* row = Y + (size_t)(p0 + pp) * 1024 + tid;
#pragma unroll
        for (int j = 0; j < 4; ++j) {
            float v = row[256 * j];
            s[j] += v;
            q[j] += v * v;
        }
    }
#pragma unroll
    for (int j = 0; j < 4; ++j) {
        atomicAdd(&st[tid + 256 * j], s[j]);
        atomicAdd(&st[1024 + tid + 256 * j], q[j]);
    }
}

__global__ __launch_bounds__(256) void bn_final(float* __restrict__ st,
                                                const float* __restrict__ gamma,
                                                const float* __restrict__ beta) {
    int c = blockIdx.x * 256 + threadIdx.x;
    if (c >= 1024) return;
    const float invn = 1.f / 6912.f;
    float mean = st[c] * invn;
    float var = st[1024 + c] * invn - mean * mean;
    float sc = gamma[c] * rsqrtf(var + 1e-5f);
    st[2048 + c] = sc;
    st[3072 + c] = beta[c] - mean * sc;
}

__global__ __launch_bounds__(256) void bn_apply(float* __restrict__ Y,
                                                const float* __restrict__ st) {
    const float* scale = st + 2048;
    const float* shift = st + 3072;
    int idx = blockIdx.x * 256 + threadIdx.x;  // over P_CTX*1024/4
    float4* Y4 = (float4*)Y;
    int c0 = (idx & 255) << 2;
    float4 v = Y4[idx];
    v.x = v.x * scale[c0 + 0] + shift[c0 + 0];
    v.y = v.y * scale[c0 + 1] + shift[c0 + 1];
    v.z = v.z * scale[c0 + 2] + shift[c0 + 2];
    v.w = v.w * scale[c0 + 3] + shift[c0 + 3];
    Y4[idx] = v;
}

// --------------------------- final goal/state attention ----------------------
// Hp2 [32*2304][128] pixel-major == state_embed[n, d, s] transposed.
// goal_rep[n] = goal_embed[n % 8] (faithful to torch .repeat tiling).
__global__ __launch_bounds__(256) void attn_final(const float* __restrict__ Hp2,
                                                  float* __restrict__ out) {
    __shared__ __align__(16) float sGoal[128];
    __shared__ float sAttn[S2];
    __shared__ float red[256];
    int n = blockIdx.x, tid = threadIdx.x;
    if (tid < 128) sGoal[tid] = out[(n & 7) * 128 + tid];
    __syncthreads();
    const float scale = 0.0883883476483184f;  // 1/sqrt(128)
    float lmax = -3.4e38f;
    for (int s = tid; s < S2; s += 256) {
        const float4* row = (const float4*)(Hp2 + (size_t)(n * S2 + s) * 128);
        const float4* g4 = (const float4*)sGoal;
        float a = 0.f;
#pragma unroll
        for (int q = 0; q < 32; ++q) {
            float4 v = row[q], g = g4[q];
            a += v.x * g.x + v.y * g.y + v.z * g.z + v.w * g.w;
        }
        a *= scale;
        sAttn[s] = a;
        lmax = fmaxf(lmax, a);
    }
    red[tid] = lmax;
    __syncthreads();
    for (int off = 128; off > 0; off >>= 1) {
        if (tid < off) red[tid] = fmaxf(red[tid], red[tid + off]);
        __syncthreads();
    }
    float m = red[0];
    __syncthreads();
    float lsum = 0.f;
    for (int s = tid; s < S2; s += 256) {
        float e = expf(sAttn[s] - m);
        sAttn[s] = e;
        lsum += e;
    }
    red[tid] = lsum;
    __syncthreads();
    for (int off = 128; off > 0; off >>= 1) {
        if (tid < off) red[tid] += red[tid + off];
        __syncthreads();
    }
    float inv = 1.f / red[0];
    if (tid < 128) {
        int d = tid;
        float freq = expf(-(float)(d & ~1) * (9.210340371976184f / 128.f));
        bool odd = d & 1;
        float acc = 0.f;
        for (int s = 0; s < S2; ++s) {
            float ang = (float)s * freq;
            float pe = odd ? cosf(ang) : sinf(ang);
            acc += sAttn[s] * (Hp2[(size_t)(n * S2 + s) * 128 + d] + pe);
        }
        out[1024 + n * 128 + d] = acc * inv;
    }
}

// --------------------------- launch ------------------------------------------

extern "C" void kernel_launch(void* const* d_in, const int* in_sizes, int n_in,
                              void* d_out, int out_size, void* d_ws, size_t ws_size,
                              hipStream_t stream) {
    const float* context = (const float*)d_in[0];
    const float* frame = (const float*)d_in[1];
    // d_in[2..5]: nl_Kw/Kb/Qw/Qb — unused (softmax rowsum == 1, see header)
    const float* Vw = (const float*)d_in[6];
    const float* Vb = (const float*)d_in[7];
    const float* Ow = (const float*)d_in[8];
    const float* Ob = (const float*)d_in[9];
    const float* gamma = (const float*)d_in[10];
    const float* beta = (const float*)d_in[11];
    const float* tpw = (const float*)d_in[12];
    const float* tpb = (const float*)d_in[13];
    const float* u1w = (const float*)d_in[14];
    const float* u1b = (const float*)d_in[15];
    const float* u2w = (const float*)d_in[16];
    const float* u2b = (const float*)d_in[17];
    float* ws = (float*)d_ws;
    float* out = (float*)d_out;

    float* X0 = ws + OFF_X0;
    float* X1 = ws + OFF_X1;
    float* VN = ws + OFF_VN;
    float* WT1 = ws + OFF_WT1;
    float* WT2 = ws + OFF_WT2;
    float* ST = ws + OFF_STATS;
    float* GP = ws + OFF_GP;    // alias X1.. (dead after nonlocal loop)
    float* TWT = ws + OFF_TWT;
    float* R = ws + OFF_R;
    float* HP2 = ws + OFF_HP2;  // phase C aliases
    float* HP1 = ws + OFF_HP1;
    float* F0 = ws + OFF_F0;
    float* W1T = ws + OFF_W1T;
    float* W2T = ws + OFF_W2T;

    // context [8][6][1024][144] -> X0 [6912][1024]
    transpose_cm_pm<<<dim3(HWP / 16, DIN / 64, B_ * TC), dim3(16, 16), 0, stream>>>(
        context, X0, DIN, HWP);

    float* Xin = X0;
    float* Y = X1;
    for (int l = 0; l < 2; ++l) {
        wt_oc<<<(DFF * DIN + 255) / 256, 256, 0, stream>>>(Vw + (size_t)l * DFF * DIN, WT1, DFF, DIN);
        wt_oc<<<(DIN * DFF + 255) / 256, 256, 0, stream>>>(Ow + (size_t)l * DIN * DFF, WT2, DIN, DFF);
        // Vn = relu(X*Vw^T + Vb)
        gemm_f32<1, 0, 0><<<dim3(DFF / 128, P_CTX / 128), 256, 0, stream>>>(
            Xin, WT1, Vb + l * DFF, nullptr, VN, P_CTX, DFF, DIN, 0, 0, 0, 0, 0, 0);
        // Y = X + relu(Vn*Ow^T + Ob)
        gemm_f32<1, 1, 0><<<dim3(DIN / 128, P_CTX / 128), 256, 0, stream>>>(
            VN, WT2, Ob + l * DIN, Xin, Y, P_CTX, DIN, DFF, 0, 0, 0, 0, 0, 0);
        // BatchNorm (training-mode batch stats) in place on Y
        zero_f32<<<8, 256, 0, stream>>>(ST, 2048);
        bn_stats<<<P_CTX / 64, 256, 0, stream>>>(Y, ST);
        bn_final<<<4, 256, 0, stream>>>(ST, gamma + l * DIN, beta + l * DIN);
        bn_apply<<<(P_CTX * DIN / 4) / 256, 256, 0, stream>>>(Y, ST);
        float* t = Xin;
        Xin = Y;
        Y = t;
    }
    // Xin == X0 now (final non-local output)

    // temporal pool -> goal_embed (split-K GEMM over 27 taps)
    tw_conv_t<<<(27 * DIN * DOUT + 255) / 256, 256, 0, stream>>>(tpw, TWT);
    gemm_conv3<<<dim3(27, NPOS / 128), 256, 0, stream>>>(Xin, TWT, GP);
    conv3_reduce<<<(NPOS * DOUT) / 256, 256, 0, stream>>>(GP, tpb, R);
    goal_reduce<<<8, 128, 0, stream>>>(R, tpb, out);

    // frame upsample path
    transpose_cm_pm<<<dim3(HWP / 16, DIN / 64, NF), dim3(16, 16), 0, stream>>>(
        frame, F0, DIN, HWP);
    up_w_t<<<(4 * DIN * DFF + 255) / 256, 256, 0, stream>>>(u1w, W1T, DIN, DFF);
    up_w_t<<<(4 * DFF * DOUT + 255) / 256, 256, 0, stream>>>(u2w, W2T, DFF, DOUT);
    for (int d = 0; d < 4; ++d) {
        int dh = d >> 1, dw = d & 1;
        gemm_f32<1, 0, 1><<<dim3(DFF / 128, P_FRM / 128), 256, 0, stream>>>(
            F0, W1T + (size_t)d * DIN * DFF, u1b, nullptr, HP1, P_FRM, DFF, DIN,
            12, 144, 24, dh, dw, 576);
    }
    for (int d = 0; d < 4; ++d) {
        int dh = d >> 1, dw = d & 1;
        gemm_f32<0, 0, 1><<<dim3(DOUT / 128, P_H1 / 128), 256, 0, stream>>>(
            HP1, W2T + (size_t)d * DFF * DOUT, u2b, nullptr, HP2, P_H1, DOUT, DFF,
            24, 576, 48, dh, dw, 2304);
    }

    // final goal/state attention (+ positional encoding computed on the fly)
    attn_final<<<NF, 256, 0, stream>>>(HP2, out);
}

// Round 3
// 1996.727 us; speedup vs baseline: 2.6093x; 1.5013x over previous
//
#include <hip/hip_runtime.h>
#include <cstddef>
#include <cstdint>

// ---------------------------------------------------------------------------
// AttentionGoalState — f32, round 3: final attention parallelized.
//
// Key simplification (mathematically exact up to fp rounding):
//   attn = softmax(KQ, axis=2); Vn = V * attn.sum(axis=2)  ==>  rowsums == 1
//   so Vn == V, and K/Q GEMMs + S^2 softmax are skipped entirely.
//
// Layouts: pixel-major [P, C] everywhere; convs become GEMMs.
// ---------------------------------------------------------------------------

static constexpr int B_ = 8, TC = 6, TF = 4, DIN = 1024, DFF = 512, DOUT = 128;
static constexpr int HWP = 144;                  // 12*12
static constexpr int P_CTX = B_ * TC * HWP;      // 6912
static constexpr int NF = B_ * TF;               // 32
static constexpr int P_FRM = NF * HWP;           // 4608
static constexpr int P_H1 = NF * 24 * 24;        // 18432
static constexpr int P_H2 = NF * 48 * 48;        // 73728
static constexpr int S2 = 48 * 48;               // 2304
static constexpr int NPOS = 3200;                // 8*4*10*10 conv3d outputs

// workspace offsets in floats (phase-aliased; peak ~104 MB)
static constexpr size_t OFF_X0    = 0;
static constexpr size_t OFF_X1    = OFF_X0 + (size_t)P_CTX * DIN;    // 7077888
static constexpr size_t OFF_VN    = OFF_X1 + (size_t)P_CTX * DIN;    // 14155776
static constexpr size_t OFF_WT1   = OFF_VN + (size_t)P_CTX * DFF;    // 17694720
static constexpr size_t OFF_WT2   = OFF_WT1 + (size_t)DFF * DIN;     // 18219008
static constexpr size_t OFF_STATS = OFF_WT2 + (size_t)DFF * DIN;     // 18743296
// conv3d phase (X1/VN/WT*/STATS dead; X0 still live):
static constexpr size_t OFF_GP    = OFF_X1;                           // 27*3200*128
static constexpr size_t OFF_TWT   = OFF_GP + (size_t)27 * NPOS * DOUT;
static constexpr size_t OFF_R     = OFF_TWT + (size_t)27 * DIN * DOUT;
// upsample phase (everything above dead):
static constexpr size_t OFF_HP2   = 0;
static constexpr size_t OFF_HP1   = OFF_HP2 + (size_t)P_H2 * DOUT;   // 9437184
static constexpr size_t OFF_F0    = OFF_HP1 + (size_t)P_H1 * DFF;    // 18874368
static constexpr size_t OFF_W1T   = OFF_F0 + (size_t)P_FRM * DIN;    // 23592960
static constexpr size_t OFF_W2T   = OFF_W1T + (size_t)4 * DIN * DFF; // 25690112
// attention phase (HP1 dead once HP2 is built): SG + PP alias HP1
static constexpr size_t OFF_SG    = OFF_HP1;                          // 32*2304
static constexpr size_t OFF_PP    = OFF_SG + (size_t)NF * S2;         // 32*18*256

// --------------------------- helpers ---------------------------------------

__global__ __launch_bounds__(256) void zero_f32(float* p, int n) {
    int i = blockIdx.x * 256 + threadIdx.x;
    if (i < n) p[i] = 0.f;
}

// [F][C][HW] -> [F*HW][C]  (tiled transpose, both sides coalesced)
__global__ __launch_bounds__(256) void transpose_cm_pm(const float* __restrict__ in,
                                                       float* __restrict__ out,
                                                       int C, int HW) {
    __shared__ float T[64][17];
    int tx = threadIdx.x, ty = threadIdx.y;
    int f = blockIdx.z, hw0 = blockIdx.x * 16, c0 = blockIdx.y * 64;
#pragma unroll
    for (int i = 0; i < 4; ++i)
        T[ty + 16 * i][tx] = in[((size_t)f * C + c0 + ty + 16 * i) * HW + hw0 + tx];
    __syncthreads();
#pragma unroll
    for (int i = 0; i < 4; ++i)
        out[((size_t)f * HW + hw0 + ty) * C + c0 + tx + 16 * i] = T[tx + 16 * i][ty];
}

// out[c*O + o] = in[o*C + c]
__global__ __launch_bounds__(256) void wt_oc(const float* __restrict__ in,
                                             float* __restrict__ out, int O, int C) {
    int idx = blockIdx.x * 256 + threadIdx.x;
    if (idx >= O * C) return;
    int o = idx % O, c = idx / O;
    out[idx] = in[(size_t)o * C + c];
}

// tp_w [128][1024][27] -> Tw [27][1024][128]
__global__ __launch_bounds__(256) void tw_conv_t(const float* __restrict__ tp,
                                                 float* __restrict__ Tw) {
    int idx = blockIdx.x * 256 + threadIdx.x;
    if (idx >= 27 * 1024 * 128) return;
    int o = idx & 127, r = idx >> 7;
    int c = r & 1023, tap = r >> 10;
    Tw[idx] = tp[((size_t)o * 1024 + c) * 27 + tap];
}

// up_w [Cin][Cout][2][2] -> [4][Cin][Cout]
__global__ __launch_bounds__(256) void up_w_t(const float* __restrict__ win,
                                              float* __restrict__ wout, int Cin, int Cout) {
    int idx = blockIdx.x * 256 + threadIdx.x;
    if (idx >= 4 * Cin * Cout) return;
    int o = idx % Cout, r = idx / Cout;
    int c = r % Cin, d = r / Cin;
    wout[idx] = win[((size_t)c * Cout + o) * 4 + d];
}

// --------------------------- GEMM ------------------------------------------
// C[M,N] = op(A[M,K] x B[K,N] + bias), optional relu / residual / out-row remap.
// BM=BN=128, BK=16, 256 threads, 8x8 per thread. All dims divide exactly here.
template <int RELU, int RESID, int REMAP>
__global__ __launch_bounds__(256) void gemm_f32(
    const float* __restrict__ A, const float* __restrict__ B,
    const float* __restrict__ bias, const float* __restrict__ resid,
    float* __restrict__ C, int M, int N, int K,
    int inW, int inHW, int outW, int dh, int dw, int outSPP) {
    __shared__ float As[16][132];
    __shared__ float Bs[16][132];
    int tid = threadIdx.x;
    int tx = tid & 15, ty = tid >> 4;
    int m0 = blockIdx.y * 128, n0 = blockIdx.x * 128;
    float acc[8][8] = {};

    for (int k0 = 0; k0 < K; k0 += 16) {
#pragma unroll
        for (int i = 0; i < 8; ++i) {
            int e = tid + i * 256;
            int am = e >> 4, ak = e & 15;
            As[ak][am] = A[(size_t)(m0 + am) * K + k0 + ak];
        }
#pragma unroll
        for (int i = 0; i < 8; ++i) {
            int e = tid + i * 256;
            int bk = e >> 7, bn = e & 127;
            Bs[bk][bn] = B[(size_t)(k0 + bk) * N + n0 + bn];
        }
        __syncthreads();
#pragma unroll
        for (int k = 0; k < 16; ++k) {
            float a[8], b[8];
#pragma unroll
            for (int i = 0; i < 8; ++i) a[i] = As[k][ty + 16 * i];
#pragma unroll
            for (int j = 0; j < 8; ++j) b[j] = Bs[k][tx + 16 * j];
#pragma unroll
            for (int i = 0; i < 8; ++i)
#pragma unroll
                for (int j = 0; j < 8; ++j) acc[i][j] += a[i] * b[j];
        }
        __syncthreads();
    }

#pragma unroll
    for (int i = 0; i < 8; ++i) {
        int m = m0 + ty + 16 * i;
        int orow;
        if (REMAP) {
            int ni = m / inHW;
            int rem = m - ni * inHW;
            int h = rem / inW, w = rem - h * inW;
            orow = ni * outSPP + (2 * h + dh) * outW + (2 * w + dw);
        } else {
            orow = m;
        }
        const float* rrow = RESID ? resid + (size_t)m * N : nullptr;
        float* crow = C + (size_t)orow * N;
#pragma unroll
        for (int j = 0; j < 8; ++j) {
            int n = n0 + tx + 16 * j;
            float v = acc[i][j] + bias[n];
            if (RELU) v = fmaxf(v, 0.f);
            if (RESID) v += rrow[n];
            crow[n] = v;
        }
    }
}

// ---------------- conv3d as split-K GEMM ------------------------------------
// X pixel-major [6912][1024]; Tw [27][1024][128].
// grid (27 taps, 25 M-blocks); each block: [128 pos,1024ch] x [1024,128] f32.
__global__ __launch_bounds__(256) void gemm_conv3(const float* __restrict__ X,
                                                  const float* __restrict__ Tw,
                                                  float* __restrict__ Gp) {
    __shared__ float As[16][132];
    __shared__ float Bs[16][132];
    __shared__ int sPix[128];
    int tid = threadIdx.x;
    int tap = blockIdx.x;
    int m0 = blockIdx.y * 128;
    int dt = tap / 9, rr = tap - dt * 9;
    int doff = dt * 144 + (rr / 3) * 12 + (rr % 3);
    if (tid < 128) {
        int pos = m0 + tid;
        int w = pos % 10;
        int r = pos / 10;
        int h = r % 10;
        r /= 10;
        int t = r & 3, b = r >> 2;
        sPix[tid] = ((b * 6 + t) * 12 + h) * 12 + w + doff;  // input row
    }
    __syncthreads();
    int tx = tid & 15, ty = tid >> 4;
    size_t rowb[8];
#pragma unroll
    for (int i = 0; i < 8; ++i) rowb[i] = (size_t)sPix[(tid >> 4) + 16 * i] * 1024;
    const float* Bw = Tw + (size_t)tap * 1024 * 128;
    float acc[8][8] = {};

    for (int k0 = 0; k0 < 1024; k0 += 16) {
#pragma unroll
        for (int i = 0; i < 8; ++i) {
            int am = (tid >> 4) + 16 * i, ak = tid & 15;
            As[ak][am] = X[rowb[i] + k0 + ak];
        }
#pragma unroll
        for (int i = 0; i < 8; ++i) {
            int e = tid + i * 256;
            int bk = e >> 7, bn = e & 127;
            Bs[bk][bn] = Bw[(size_t)(k0 + bk) * 128 + bn];
        }
        __syncthreads();
#pragma unroll
        for (int k = 0; k < 16; ++k) {
            float a[8], b[8];
#pragma unroll
            for (int i = 0; i < 8; ++i) a[i] = As[k][ty + 16 * i];
#pragma unroll
            for (int j = 0; j < 8; ++j) b[j] = Bs[k][tx + 16 * j];
#pragma unroll
            for (int i = 0; i < 8; ++i)
#pragma unroll
                for (int j = 0; j < 8; ++j) acc[i][j] += a[i] * b[j];
        }
        __syncthreads();
    }

    float* Go = Gp + (size_t)tap * NPOS * 128 + (size_t)m0 * 128;
#pragma unroll
    for (int i = 0; i < 8; ++i)
#pragma unroll
        for (int j = 0; j < 8; ++j)
            Go[(size_t)(ty + 16 * i) * 128 + tx + 16 * j] = acc[i][j];
}

// sum 27 tap-partials, + bias, relu -> R[3200][128]
__global__ __launch_bounds__(256) void conv3_reduce(const float* __restrict__ Gp,
                                                    const float* __restrict__ bias,
                                                    float* __restrict__ R) {
    int idx = blockIdx.x * 256 + threadIdx.x;  // 3200*128
    float s = 0.f;
    for (int tap = 0; tap < 27; ++tap) s += Gp[(size_t)tap * (NPOS * 128) + idx];
    R[idx] = fmaxf(s + bias[idx & 127], 0.f);
}

// mean over 400 positions -> goal_embed [8][128] (front of d_out)
__global__ __launch_bounds__(128) void goal_reduce(const float* __restrict__ R,
                                                   float* __restrict__ out) {
    int b = blockIdx.x, o = threadIdx.x;
    float s = 0.f;
    for (int i = 0; i < 400; ++i) s += R[(size_t)(b * 400 + i) * 128 + o];
    out[b * 128 + o] = s * (1.f / 400.f);
}

// --------------------------- BatchNorm --------------------------------------

__global__ __launch_bounds__(256) void bn_stats(const float* __restrict__ Y,
                                                float* __restrict__ st) {
    int tid = threadIdx.x;
    int p0 = blockIdx.x * 64;
    float s[4] = {0, 0, 0, 0}, q[4] = {0, 0, 0, 0};
    for (int pp = 0; pp < 64; ++pp) {
        const float* row = Y + (size_t)(p0 + pp) * 1024 + tid;
#pragma unroll
        for (int j = 0; j < 4; ++j) {
            float v = row[256 * j];
            s[j] += v;
            q[j] += v * v;
        }
    }
#pragma unroll
    for (int j = 0; j < 4; ++j) {
        atomicAdd(&st[tid + 256 * j], s[j]);
        atomicAdd(&st[1024 + tid + 256 * j], q[j]);
    }
}

__global__ __launch_bounds__(256) void bn_final(float* __restrict__ st,
                                                const float* __restrict__ gamma,
                                                const float* __restrict__ beta) {
    int c = blockIdx.x * 256 + threadIdx.x;
    if (c >= 1024) return;
    const float invn = 1.f / 6912.f;
    float mean = st[c] * invn;
    float var = st[1024 + c] * invn - mean * mean;
    float sc = gamma[c] * rsqrtf(var + 1e-5f);
    st[2048 + c] = sc;
    st[3072 + c] = beta[c] - mean * sc;
}

__global__ __launch_bounds__(256) void bn_apply(float* __restrict__ Y,
                                                const float* __restrict__ st) {
    const float* scale = st + 2048;
    const float* shift = st + 3072;
    int idx = blockIdx.x * 256 + threadIdx.x;  // over P_CTX*1024/4
    float4* Y4 = (float4*)Y;
    int c0 = (idx & 255) << 2;
    float4 v = Y4[idx];
    v.x = v.x * scale[c0 + 0] + shift[c0 + 0];
    v.y = v.y * scale[c0 + 1] + shift[c0 + 1];
    v.z = v.z * scale[c0 + 2] + shift[c0 + 2];
    v.w = v.w * scale[c0 + 3] + shift[c0 + 3];
    Y4[idx] = v;
}

// --------------------------- final goal/state attention ----------------------
// Hp2 [32*2304][128] pixel-major; goal_rep[n] = goal_embed[n % 8].
// Stage 1: logits SG[n][s] = <Hp2[n,s,:], goal[n%8,:]> / sqrt(128)
__global__ __launch_bounds__(256) void attn_logits(const float* __restrict__ Hp2,
                                                   const float* __restrict__ out,
                                                   float* __restrict__ SG) {
    int n = blockIdx.y;
    int tid = threadIdx.x;
    int s = blockIdx.x * 16 + (tid >> 4);
    int l16 = tid & 15;
    const float4* row = (const float4*)(Hp2 + ((size_t)n * S2 + s) * 128 + l16 * 8);
    const float4* g = (const float4*)(out + (n & 7) * 128 + l16 * 8);
    float4 a0 = row[0], a1 = row[1], g0 = g[0], g1 = g[1];
    float dot = a0.x * g0.x + a0.y * g0.y + a0.z * g0.z + a0.w * g0.w +
                a1.x * g1.x + a1.y * g1.y + a1.z * g1.z + a1.w * g1.w;
    dot += __shfl_xor(dot, 1);
    dot += __shfl_xor(dot, 2);
    dot += __shfl_xor(dot, 4);
    dot += __shfl_xor(dot, 8);
    if (l16 == 0) SG[(size_t)n * S2 + s] = dot * 0.0883883476483184f;
}

// Stage 2: softmax in place over s (one block per n)
__global__ __launch_bounds__(256) void attn_softmax(float* __restrict__ SG) {
    __shared__ float red[256];
    int n = blockIdx.x, tid = threadIdx.x;
    float* row = SG + (size_t)n * S2;
    float v[9];
    float lmax = -3.4e38f;
#pragma unroll
    for (int i = 0; i < 9; ++i) {
        v[i] = row[tid + 256 * i];
        lmax = fmaxf(lmax, v[i]);
    }
    red[tid] = lmax;
    __syncthreads();
    for (int off = 128; off > 0; off >>= 1) {
        if (tid < off) red[tid] = fmaxf(red[tid], red[tid + off]);
        __syncthreads();
    }
    float m = red[0];
    __syncthreads();
    float ls = 0.f;
#pragma unroll
    for (int i = 0; i < 9; ++i) {
        v[i] = expf(v[i] - m);
        ls += v[i];
    }
    red[tid] = ls;
    __syncthreads();
    for (int off = 128; off > 0; off >>= 1) {
        if (tid < off) red[tid] += red[tid + off];
        __syncthreads();
    }
    float inv = 1.f / red[0];
#pragma unroll
    for (int i = 0; i < 9; ++i) row[tid + 256 * i] = v[i] * inv;
}

// Stage 3: PV partials. grid (18, 32); block covers 128 s; thread: d=tid&127,
// half=tid>>7 handles 64 s. PE computed on the fly.
__global__ __launch_bounds__(256) void attn_pv(const float* __restrict__ Hp2,
                                               const float* __restrict__ SG,
                                               float* __restrict__ PP) {
    int n = blockIdx.y;
    int sb = blockIdx.x;
    int tid = threadIdx.x;
    int d = tid & 127, half = tid >> 7;
    int s0 = sb * 128 + half * 64;
    float freq = expf(-(float)(d & ~1) * (9.210340371976184f / 128.f));
    bool odd = d & 1;
    const float* att = SG + (size_t)n * S2;
    float acc = 0.f;
    for (int i = 0; i < 64; ++i) {
        int s = s0 + i;
        float ang = (float)s * freq;
        float pe = odd ? cosf(ang) : sinf(ang);
        acc += att[s] * (Hp2[((size_t)n * S2 + s) * 128 + d] + pe);
    }
    PP[((size_t)n * 18 + sb) * 256 + tid] = acc;
}

// Stage 4: reduce 36 partials per (n,d) -> out[1024 + n*128 + d]
__global__ __launch_bounds__(128) void attn_pv_reduce(const float* __restrict__ PP,
                                                      float* __restrict__ out) {
    int n = blockIdx.x, d = threadIdx.x;
    float s = 0.f;
    for (int i = 0; i < 18; ++i) {
        const float* p = PP + ((size_t)n * 18 + i) * 256;
        s += p[d] + p[128 + d];
    }
    out[1024 + n * 128 + d] = s;
}

// --------------------------- launch ------------------------------------------

extern "C" void kernel_launch(void* const* d_in, const int* in_sizes, int n_in,
                              void* d_out, int out_size, void* d_ws, size_t ws_size,
                              hipStream_t stream) {
    const float* context = (const float*)d_in[0];
    const float* frame = (const float*)d_in[1];
    // d_in[2..5]: nl_Kw/Kb/Qw/Qb — unused (softmax rowsum == 1, see header)
    const float* Vw = (const float*)d_in[6];
    const float* Vb = (const float*)d_in[7];
    const float* Ow = (const float*)d_in[8];
    const float* Ob = (const float*)d_in[9];
    const float* gamma = (const float*)d_in[10];
    const float* beta = (const float*)d_in[11];
    const float* tpw = (const float*)d_in[12];
    const float* tpb = (const float*)d_in[13];
    const float* u1w = (const float*)d_in[14];
    const float* u1b = (const float*)d_in[15];
    const float* u2w = (const float*)d_in[16];
    const float* u2b = (const float*)d_in[17];
    float* ws = (float*)d_ws;
    float* out = (float*)d_out;

    float* X0 = ws + OFF_X0;
    float* X1 = ws + OFF_X1;
    float* VN = ws + OFF_VN;
    float* WT1 = ws + OFF_WT1;
    float* WT2 = ws + OFF_WT2;
    float* ST = ws + OFF_STATS;
    float* GP = ws + OFF_GP;
    float* TWT = ws + OFF_TWT;
    float* R = ws + OFF_R;
    float* HP2 = ws + OFF_HP2;
    float* HP1 = ws + OFF_HP1;
    float* F0 = ws + OFF_F0;
    float* W1T = ws + OFF_W1T;
    float* W2T = ws + OFF_W2T;
    float* SG = ws + OFF_SG;
    float* PP = ws + OFF_PP;

    // context [8][6][1024][144] -> X0 [6912][1024]
    transpose_cm_pm<<<dim3(HWP / 16, DIN / 64, B_ * TC), dim3(16, 16), 0, stream>>>(
        context, X0, DIN, HWP);

    float* Xin = X0;
    float* Y = X1;
    for (int l = 0; l < 2; ++l) {
        wt_oc<<<(DFF * DIN + 255) / 256, 256, 0, stream>>>(Vw + (size_t)l * DFF * DIN, WT1, DFF, DIN);
        wt_oc<<<(DIN * DFF + 255) / 256, 256, 0, stream>>>(Ow + (size_t)l * DIN * DFF, WT2, DIN, DFF);
        // Vn = relu(X*Vw^T + Vb)
        gemm_f32<1, 0, 0><<<dim3(DFF / 128, P_CTX / 128), 256, 0, stream>>>(
            Xin, WT1, Vb + l * DFF, nullptr, VN, P_CTX, DFF, DIN, 0, 0, 0, 0, 0, 0);
        // Y = X + relu(Vn*Ow^T + Ob)
        gemm_f32<1, 1, 0><<<dim3(DIN / 128, P_CTX / 128), 256, 0, stream>>>(
            VN, WT2, Ob + l * DIN, Xin, Y, P_CTX, DIN, DFF, 0, 0, 0, 0, 0, 0);
        // BatchNorm (training-mode batch stats) in place on Y
        zero_f32<<<8, 256, 0, stream>>>(ST, 2048);
        bn_stats<<<P_CTX / 64, 256, 0, stream>>>(Y, ST);
        bn_final<<<4, 256, 0, stream>>>(ST, gamma + l * DIN, beta + l * DIN);
        bn_apply<<<(P_CTX * DIN / 4) / 256, 256, 0, stream>>>(Y, ST);
        float* t = Xin;
        Xin = Y;
        Y = t;
    }
    // Xin == X0 now (final non-local output)

    // temporal pool -> goal_embed (split-K GEMM over 27 taps)
    tw_conv_t<<<(27 * DIN * DOUT + 255) / 256, 256, 0, stream>>>(tpw, TWT);
    gemm_conv3<<<dim3(27, NPOS / 128), 256, 0, stream>>>(Xin, TWT, GP);
    conv3_reduce<<<(NPOS * DOUT) / 256, 256, 0, stream>>>(GP, tpb, R);
    goal_reduce<<<8, 128, 0, stream>>>(R, out);

    // frame upsample path
    transpose_cm_pm<<<dim3(HWP / 16, DIN / 64, NF), dim3(16, 16), 0, stream>>>(
        frame, F0, DIN, HWP);
    up_w_t<<<(4 * DIN * DFF + 255) / 256, 256, 0, stream>>>(u1w, W1T, DIN, DFF);
    up_w_t<<<(4 * DFF * DOUT + 255) / 256, 256, 0, stream>>>(u2w, W2T, DFF, DOUT);
    for (int d = 0; d < 4; ++d) {
        int dh = d >> 1, dw = d & 1;
        gemm_f32<1, 0, 1><<<dim3(DFF / 128, P_FRM / 128), 256, 0, stream>>>(
            F0, W1T + (size_t)d * DIN * DFF, u1b, nullptr, HP1, P_FRM, DFF, DIN,
            12, 144, 24, dh, dw, 576);
    }
    for (int d = 0; d < 4; ++d) {
        int dh = d >> 1, dw = d & 1;
        gemm_f32<0, 0, 1><<<dim3(DOUT / 128, P_H1 / 128), 256, 0, stream>>>(
            HP1, W2T + (size_t)d * DFF * DOUT, u2b, nullptr, HP2, P_H1, DOUT, DFF,
            24, 576, 48, dh, dw, 2304);
    }

    // final goal/state attention (parallel: logits -> softmax -> PV -> reduce)
    attn_logits<<<dim3(S2 / 16, NF), 256, 0, stream>>>(HP2, out, SG);
    attn_softmax<<<NF, 256, 0, stream>>>(SG);
    attn_pv<<<dim3(18, NF), 256, 0, stream>>>(HP2, SG, PP);
    attn_pv_reduce<<<NF, 128, 0, stream>>>(PP, out);
}

// Round 4
// 363.253 us; speedup vs baseline: 14.3426x; 5.4968x over previous
//
#include <hip/hip_runtime.h>
#include <cstddef>
#include <cstdint>

// ---------------------------------------------------------------------------
// AttentionGoalState — round 4: all GEMMs -> bf16 MFMA (16x16x32).
//
// Simplifications (exact up to fp rounding):
//   attn = softmax(KQ); Vn = V * attn.sum(axis=2) == V  (rowsums == 1)
//   -> K/Q GEMMs + S^2 softmax skipped entirely.
//
// GEMM structure (m97-style): 128x128 tile, 4 waves, each wave 64x64 via
// 4x4 fragments of mfma_f32_16x16x32_bf16, BK=32, global_load_lds(16B)
// staging, 2-barrier K-loop.  A: row-major bf16.  B: pre-interleaved
// [K/8][N][8] so B-fragment reads are contiguous ds_read_b128.
// ---------------------------------------------------------------------------

static constexpr int B_ = 8, TC = 6, TF = 4, DIN = 1024, DFF = 512, DOUT = 128;
static constexpr int HWP = 144;
static constexpr int P_CTX = B_ * TC * HWP;      // 6912
static constexpr int NF = B_ * TF;               // 32
static constexpr int P_FRM = NF * HWP;           // 4608
static constexpr int P_H1 = NF * 24 * 24;        // 18432
static constexpr int P_H2 = NF * 48 * 48;        // 73728
static constexpr int S2 = 48 * 48;               // 2304
static constexpr int NPOS = 3200;                // 8*4*10*10 conv3d outputs

// workspace offsets in float slots (phase-aliased; peak < 20.0M floats = 80MB)
static constexpr size_t OFF_X0   = 0;                              // 7,077,888 f32
static constexpr size_t OFF_X1   = 7077888;                        // 7,077,888 f32
static constexpr size_t OFF_XB   = 14155776;                       // 7,077,888 bf16 (3,538,944 slots)
static constexpr size_t OFF_VNB  = 17694720;                       // 3,538,944 bf16 (1,769,472 slots)
static constexpr size_t OFF_WB1  = 19464192;                       // 524,288 bf16 (262,144 slots)
static constexpr size_t OFF_WB2  = 19726336;                       // 524,288 bf16
static constexpr size_t OFF_ST   = 19988480;                       // 4,096 f32
// conv3d phase (over X0/X1; XB still live):
static constexpr size_t OFF_GP   = 0;                              // 11,059,200 f32
static constexpr size_t OFF_TWB  = 11059200;                       // 3,538,944 bf16
static constexpr size_t OFF_R    = 12828672;                       // 409,600 f32
// upsample/attn phase (everything except out dead):
static constexpr size_t OFF_HP2  = 0;                              // 9,437,184 f32
static constexpr size_t OFF_HP1B = 9437184;                        // 9,437,184 bf16
static constexpr size_t OFF_F0B  = 14155776;                       // 4,718,592 bf16
static constexpr size_t OFF_W1B  = 16515072;                       // 2,097,152 bf16
static constexpr size_t OFF_W2B  = 17563648;                       // 262,144 bf16
static constexpr size_t OFF_SG   = 17694720;                       // 73,728 f32
static constexpr size_t OFF_PP   = 17768448;                       // 147,456 f32

typedef __attribute__((ext_vector_type(8))) short bf16x8;
typedef __attribute__((ext_vector_type(4))) float f32x4;
typedef __attribute__((ext_vector_type(4))) unsigned short us4;

__device__ __forceinline__ unsigned short f2b(float f) {
    union { float f; uint32_t u; } x{f};
    uint32_t r = x.u + 0x7FFFu + ((x.u >> 16) & 1u);  // RNE
    return (unsigned short)(r >> 16);
}

#define GL16(g, s)                                                        \
    __builtin_amdgcn_global_load_lds(                                     \
        (const __attribute__((address_space(1))) void*)(g),               \
        (__attribute__((address_space(3))) void*)(s), 16, 0, 0)

// --------------------------- helpers ---------------------------------------

__global__ __launch_bounds__(256) void zero_f32(float* p, int n) {
    int i = blockIdx.x * 256 + threadIdx.x;
    if (i < n) p[i] = 0.f;
}

// [F][C][HW] -> [F*HW][C], f32 and/or bf16 outputs
template <int WF32>
__global__ __launch_bounds__(256) void transpose_cm_pm(const float* __restrict__ in,
                                                       float* __restrict__ outF,
                                                       unsigned short* __restrict__ outB,
                                                       int C, int HW) {
    __shared__ float T[64][17];
    int tx = threadIdx.x, ty = threadIdx.y;
    int f = blockIdx.z, hw0 = blockIdx.x * 16, c0 = blockIdx.y * 64;
#pragma unroll
    for (int i = 0; i < 4; ++i)
        T[ty + 16 * i][tx] = in[((size_t)f * C + c0 + ty + 16 * i) * HW + hw0 + tx];
    __syncthreads();
#pragma unroll
    for (int i = 0; i < 4; ++i) {
        float v = T[tx + 16 * i][ty];
        size_t o = ((size_t)f * HW + hw0 + ty) * C + c0 + tx + 16 * i;
        if (WF32) outF[o] = v;
        outB[o] = f2b(v);
    }
}

// weight [O][C] -> Bp[((c>>3)*O + o)*8 + (c&7)]  (B[k=c][n=o])
__global__ __launch_bounds__(256) void wb_plain(const float* __restrict__ in,
                                                unsigned short* __restrict__ out,
                                                int O, int C) {
    int t = blockIdx.x * 256 + threadIdx.x;
    if (t >= O * C) return;
    int kr = t & 7, o = (t >> 3) % O, kg = (t >> 3) / O;
    out[t] = f2b(in[(size_t)o * C + kg * 8 + kr]);
}

// tp_w [128][1024][27] -> TWB[tap][((c>>3)*128 + o)*8 + (c&7)]
__global__ __launch_bounds__(256) void wb_conv(const float* __restrict__ tp,
                                               unsigned short* __restrict__ out) {
    int t = blockIdx.x * 256 + threadIdx.x;
    if (t >= 27 * 1024 * 128) return;
    int kr = t & 7, o = (t >> 3) & 127, kg = (t >> 10) & 127, tap = t >> 17;
    int c = kg * 8 + kr;
    out[t] = f2b(tp[((size_t)o * 1024 + c) * 27 + tap]);
}

// up_w [C][O][2][2] -> WB[d][((c>>3)*O + o)*8 + (c&7)]
__global__ __launch_bounds__(256) void wb_convT(const float* __restrict__ uw,
                                                unsigned short* __restrict__ out,
                                                int O, int C) {
    int t = blockIdx.x * 256 + threadIdx.x;
    if (t >= 4 * O * C) return;
    int kr = t & 7, o = (t >> 3) % O;
    int rest = (t >> 3) / O;
    int kg = rest % (C / 8), d = rest / (C / 8);
    int c = kg * 8 + kr;
    out[t] = f2b(uw[((size_t)c * O + o) * 4 + d]);
}

// --------------------------- MFMA GEMM --------------------------------------
// C[M,N] = epi(A[M,K] x B[K,N]).  A bf16 row-major (GATHER: im2col rows),
// B interleaved [K/8][N][8].  EPI bits: 1=bias 2=relu 4=resid(f32) 8=bf16 out.
// blockIdx.z: tap (conv3d: B/C offset) or quadrant d (convT REMAP dh/dw).
template <int EPI, int REMAP, int GATHER>
__global__ __launch_bounds__(256) void gemm_mfma(
    const unsigned short* __restrict__ A, const unsigned short* __restrict__ Bp,
    const float* __restrict__ bias, const float* __restrict__ resid,
    void* __restrict__ Cv, int M, int N, int K,
    size_t bStrideZ, size_t cStrideZ,
    int inW, int inHW, int outW, int outSPP) {
    __shared__ unsigned short Al[128 * 32];  // (row, k) at row*32 + k
    __shared__ unsigned short Bl[128 * 32];  // (kg, n, kr) at (kg*128+n)*8+kr
    __shared__ int sPix[128];
    int tid = threadIdx.x;
    int w = tid >> 6, l = tid & 63;
    int m0 = blockIdx.y * 128, n0 = blockIdx.x * 128;
    int z = blockIdx.z;
    const unsigned short* Bpz = Bp + (size_t)z * bStrideZ;

    if (GATHER) {
        if (tid < 128) {
            int pos = m0 + tid;
            int ww = pos % 10;
            int r = pos / 10;
            int h = r % 10;
            r /= 10;
            int t = r & 3, b = r >> 2;
            int dt = z / 9, rr = z - dt * 9;
            int doff = dt * 144 + (rr / 3) * 12 + (rr % 3);
            sPix[tid] = ((b * 6 + t) * 12 + h) * 12 + ww + doff;
        }
        __syncthreads();
    }

    // staging addresses: A rows w*32+c*16+(l>>2), 16B chunk (l&3)
    int arow0 = w * 32 + (l >> 2), arow1 = arow0 + 16;
    int grow0 = GATHER ? sPix[arow0] : (m0 + arow0);
    int grow1 = GATHER ? sPix[arow1] : (m0 + arow1);
    const unsigned short* ag0 = A + (size_t)grow0 * K + (l & 3) * 8;
    const unsigned short* ag1 = A + (size_t)grow1 * K + (l & 3) * 8;
    unsigned short* al0 = &Al[w * 1024 + l * 8];
    unsigned short* al1 = &Al[w * 1024 + 512 + l * 8];
    // B: kg=w, n = c*64 + l
    const unsigned short* bg0 = Bpz + ((size_t)w * N + n0 + l) * 8;
    const unsigned short* bg1 = bg0 + (size_t)64 * 8;
    unsigned short* bl0 = &Bl[w * 1024 + l * 8];
    unsigned short* bl1 = &Bl[w * 1024 + 512 + l * 8];
    size_t bstep = (size_t)32 * N;  // 4 k-groups * N * 8 elems

    int wr = w >> 1, wc = w & 1;
    int l15 = l & 15, lg = l >> 4;
    f32x4 acc[4][4];
#pragma unroll
    for (int mi = 0; mi < 4; ++mi)
#pragma unroll
        for (int ni = 0; ni < 4; ++ni) acc[mi][ni] = (f32x4){0.f, 0.f, 0.f, 0.f};

    for (int k0 = 0; k0 < K; k0 += 32) {
        GL16(ag0, al0);
        GL16(ag1, al1);
        GL16(bg0, bl0);
        GL16(bg1, bl1);
        ag0 += 32;
        ag1 += 32;
        bg0 += bstep;
        bg1 += bstep;
        __syncthreads();
        bf16x8 af[4], bf[4];
#pragma unroll
        for (int mi = 0; mi < 4; ++mi)
            af[mi] = *(const bf16x8*)&Al[(wr * 64 + mi * 16 + l15) * 32 + lg * 8];
#pragma unroll
        for (int ni = 0; ni < 4; ++ni)
            bf[ni] = *(const bf16x8*)&Bl[(lg * 128 + wc * 64 + ni * 16 + l15) * 8];
#pragma unroll
        for (int mi = 0; mi < 4; ++mi)
#pragma unroll
            for (int ni = 0; ni < 4; ++ni)
                acc[mi][ni] = __builtin_amdgcn_mfma_f32_16x16x32_bf16(
                    af[mi], bf[ni], acc[mi][ni], 0, 0, 0);
        __syncthreads();
    }

    // epilogue
    float bv[4];
#pragma unroll
    for (int ni = 0; ni < 4; ++ni)
        bv[ni] = (EPI & 1) ? bias[n0 + wc * 64 + ni * 16 + l15] : 0.f;
    float* Cf = (float*)Cv + (size_t)z * cStrideZ;
    unsigned short* Cb = (unsigned short*)Cv;
#pragma unroll
    for (int mi = 0; mi < 4; ++mi) {
#pragma unroll
        for (int r = 0; r < 4; ++r) {
            int m = m0 + wr * 64 + mi * 16 + lg * 4 + r;
            int orow = m;
            if (REMAP) {
                int ni_ = m / inHW;
                int rem = m - ni_ * inHW;
                int h = rem / inW, ww = rem - h * inW;
                orow = ni_ * outSPP + (2 * h + (z >> 1)) * outW + (2 * ww + (z & 1));
            }
#pragma unroll
            for (int ni = 0; ni < 4; ++ni) {
                int n = n0 + wc * 64 + ni * 16 + l15;
                float v = acc[mi][ni][r] + bv[ni];
                if (EPI & 2) v = fmaxf(v, 0.f);
                if (EPI & 4) v += resid[(size_t)m * N + n];
                if (EPI & 8)
                    Cb[(size_t)orow * N + n] = f2b(v);
                else
                    Cf[(size_t)orow * N + n] = v;
            }
        }
    }
}

// --------------------------- conv3d tail -------------------------------------

__global__ __launch_bounds__(256) void conv3_reduce(const float* __restrict__ Gp,
                                                    const float* __restrict__ bias,
                                                    float* __restrict__ R) {
    int idx = blockIdx.x * 256 + threadIdx.x;  // 3200*128
    float s = 0.f;
    for (int tap = 0; tap < 27; ++tap) s += Gp[(size_t)tap * (NPOS * 128) + idx];
    R[idx] = fmaxf(s + bias[idx & 127], 0.f);
}

__global__ __launch_bounds__(128) void goal_reduce(const float* __restrict__ R,
                                                   float* __restrict__ out) {
    int b = blockIdx.x, o = threadIdx.x;
    float s = 0.f;
    for (int i = 0; i < 400; ++i) s += R[(size_t)(b * 400 + i) * 128 + o];
    out[b * 128 + o] = s * (1.f / 400.f);
}

// --------------------------- BatchNorm --------------------------------------

__global__ __launch_bounds__(256) void bn_stats(const float* __restrict__ Y,
                                                float* __restrict__ st) {
    int tid = threadIdx.x;
    int p0 = blockIdx.x * 64;
    float s[4] = {0, 0, 0, 0}, q[4] = {0, 0, 0, 0};
    for (int pp = 0; pp < 64; ++pp) {
        const float* row = Y + (size_t)(p0 + pp) * 1024 + tid;
#pragma unroll
        for (int j = 0; j < 4; ++j) {
            float v = row[256 * j];
            s[j] += v;
            q[j] += v * v;
        }
    }
#pragma unroll
    for (int j = 0; j < 4; ++j) {
        atomicAdd(&st[tid + 256 * j], s[j]);
        atomicAdd(&st[1024 + tid + 256 * j], q[j]);
    }
}

__global__ __launch_bounds__(256) void bn_final(float* __restrict__ st,
                                                const float* __restrict__ gamma,
                                                const float* __restrict__ beta) {
    int c = blockIdx.x * 256 + threadIdx.x;
    if (c >= 1024) return;
    const float invn = 1.f / 6912.f;
    float mean = st[c] * invn;
    float var = st[1024 + c] * invn - mean * mean;
    float sc = gamma[c] * rsqrtf(var + 1e-5f);
    st[2048 + c] = sc;
    st[3072 + c] = beta[c] - mean * sc;
}

// BN apply in place on Y (f32) + bf16 copy to XB
__global__ __launch_bounds__(256) void bn_apply_b(float* __restrict__ Y,
                                                  unsigned short* __restrict__ XB,
                                                  const float* __restrict__ st) {
    const float* scale = st + 2048;
    const float* shift = st + 3072;
    int idx = blockIdx.x * 256 + threadIdx.x;  // over P_CTX*1024/4
    float4* Y4 = (float4*)Y;
    int c0 = (idx & 255) << 2;
    float4 v = Y4[idx];
    v.x = v.x * scale[c0 + 0] + shift[c0 + 0];
    v.y = v.y * scale[c0 + 1] + shift[c0 + 1];
    v.z = v.z * scale[c0 + 2] + shift[c0 + 2];
    v.w = v.w * scale[c0 + 3] + shift[c0 + 3];
    Y4[idx] = v;
    us4 b;
    b.x = f2b(v.x);
    b.y = f2b(v.y);
    b.z = f2b(v.z);
    b.w = f2b(v.w);
    ((us4*)XB)[idx] = b;
}

// --------------------------- final goal/state attention ----------------------

__global__ __launch_bounds__(256) void attn_logits(const float* __restrict__ Hp2,
                                                   const float* __restrict__ out,
                                                   float* __restrict__ SG) {
    int n = blockIdx.y;
    int tid = threadIdx.x;
    int s = blockIdx.x * 16 + (tid >> 4);
    int l16 = tid & 15;
    const float4* row = (const float4*)(Hp2 + ((size_t)n * S2 + s) * 128 + l16 * 8);
    const float4* g = (const float4*)(out + (n & 7) * 128 + l16 * 8);
    float4 a0 = row[0], a1 = row[1], g0 = g[0], g1 = g[1];
    float dot = a0.x * g0.x + a0.y * g0.y + a0.z * g0.z + a0.w * g0.w +
                a1.x * g1.x + a1.y * g1.y + a1.z * g1.z + a1.w * g1.w;
    dot += __shfl_xor(dot, 1);
    dot += __shfl_xor(dot, 2);
    dot += __shfl_xor(dot, 4);
    dot += __shfl_xor(dot, 8);
    if (l16 == 0) SG[(size_t)n * S2 + s] = dot * 0.0883883476483184f;
}

__global__ __launch_bounds__(256) void attn_softmax(float* __restrict__ SG) {
    __shared__ float red[256];
    int n = blockIdx.x, tid = threadIdx.x;
    float* row = SG + (size_t)n * S2;
    float v[9];
    float lmax = -3.4e38f;
#pragma unroll
    for (int i = 0; i < 9; ++i) {
        v[i] = row[tid + 256 * i];
        lmax = fmaxf(lmax, v[i]);
    }
    red[tid] = lmax;
    __syncthreads();
    for (int off = 128; off > 0; off >>= 1) {
        if (tid < off) red[tid] = fmaxf(red[tid], red[tid + off]);
        __syncthreads();
    }
    float m = red[0];
    __syncthreads();
    float ls = 0.f;
#pragma unroll
    for (int i = 0; i < 9; ++i) {
        v[i] = expf(v[i] - m);
        ls += v[i];
    }
    red[tid] = ls;
    __syncthreads();
    for (int off = 128; off > 0; off >>= 1) {
        if (tid < off) red[tid] += red[tid + off];
        __syncthreads();
    }
    float inv = 1.f / red[0];
#pragma unroll
    for (int i = 0; i < 9; ++i) row[tid + 256 * i] = v[i] * inv;
}

__global__ __launch_bounds__(256) void attn_pv(const float* __restrict__ Hp2,
                                               const float* __restrict__ SG,
                                               float* __restrict__ PP) {
    int n = blockIdx.y;
    int sb = blockIdx.x;
    int tid = threadIdx.x;
    int d = tid & 127, half = tid >> 7;
    int s0 = sb * 128 + half * 64;
    float freq = expf(-(float)(d & ~1) * (9.210340371976184f / 128.f));
    bool odd = d & 1;
    const float* att = SG + (size_t)n * S2;
    float acc = 0.f;
    for (int i = 0; i < 64; ++i) {
        int s = s0 + i;
        float ang = (float)s * freq;
        float pe = odd ? cosf(ang) : sinf(ang);
        acc += att[s] * (Hp2[((size_t)n * S2 + s) * 128 + d] + pe);
    }
    PP[((size_t)n * 18 + sb) * 256 + tid] = acc;
}

__global__ __launch_bounds__(128) void attn_pv_reduce(const float* __restrict__ PP,
                                                      float* __restrict__ out) {
    int n = blockIdx.x, d = threadIdx.x;
    float s = 0.f;
    for (int i = 0; i < 18; ++i) {
        const float* p = PP + ((size_t)n * 18 + i) * 256;
        s += p[d] + p[128 + d];
    }
    out[1024 + n * 128 + d] = s;
}

// --------------------------- launch ------------------------------------------

extern "C" void kernel_launch(void* const* d_in, const int* in_sizes, int n_in,
                              void* d_out, int out_size, void* d_ws, size_t ws_size,
                              hipStream_t stream) {
    const float* context = (const float*)d_in[0];
    const float* frame = (const float*)d_in[1];
    const float* Vw = (const float*)d_in[6];
    const float* Vb = (const float*)d_in[7];
    const float* Ow = (const float*)d_in[8];
    const float* Ob = (const float*)d_in[9];
    const float* gamma = (const float*)d_in[10];
    const float* beta = (const float*)d_in[11];
    const float* tpw = (const float*)d_in[12];
    const float* tpb = (const float*)d_in[13];
    const float* u1w = (const float*)d_in[14];
    const float* u1b = (const float*)d_in[15];
    const float* u2w = (const float*)d_in[16];
    const float* u2b = (const float*)d_in[17];
    float* ws = (float*)d_ws;
    float* out = (float*)d_out;

    float* X0 = ws + OFF_X0;
    float* X1 = ws + OFF_X1;
    unsigned short* XB = (unsigned short*)(ws + OFF_XB);
    unsigned short* VNB = (unsigned short*)(ws + OFF_VNB);
    unsigned short* WB1 = (unsigned short*)(ws + OFF_WB1);
    unsigned short* WB2 = (unsigned short*)(ws + OFF_WB2);
    float* ST = ws + OFF_ST;
    float* GP = ws + OFF_GP;
    unsigned short* TWB = (unsigned short*)(ws + OFF_TWB);
    float* R = ws + OFF_R;
    float* HP2 = ws + OFF_HP2;
    unsigned short* HP1B = (unsigned short*)(ws + OFF_HP1B);
    unsigned short* F0B = (unsigned short*)(ws + OFF_F0B);
    unsigned short* W1B = (unsigned short*)(ws + OFF_W1B);
    unsigned short* W2B = (unsigned short*)(ws + OFF_W2B);
    float* SG = ws + OFF_SG;
    float* PP = ws + OFF_PP;

    // context [8][6][1024][144] -> X0 f32 + XB bf16 (pixel-major)
    transpose_cm_pm<1><<<dim3(HWP / 16, DIN / 64, B_ * TC), dim3(16, 16), 0, stream>>>(
        context, X0, XB, DIN, HWP);

    float* Xin = X0;
    float* Y = X1;
    for (int l = 0; l < 2; ++l) {
        wb_plain<<<(DFF * DIN) / 256, 256, 0, stream>>>(Vw + (size_t)l * DFF * DIN, WB1, DFF, DIN);
        wb_plain<<<(DIN * DFF) / 256, 256, 0, stream>>>(Ow + (size_t)l * DIN * DFF, WB2, DIN, DFF);
        // VN = relu(X*Vw^T + Vb)  [bf16 out]
        gemm_mfma<11, 0, 0><<<dim3(DFF / 128, P_CTX / 128, 1), 256, 0, stream>>>(
            XB, WB1, Vb + l * DFF, nullptr, VNB, P_CTX, DFF, DIN, 0, 0, 0, 0, 0, 0);
        // Y = X + relu(VN*Ow^T + Ob)  [f32 out]
        gemm_mfma<7, 0, 0><<<dim3(DIN / 128, P_CTX / 128, 1), 256, 0, stream>>>(
            VNB, WB2, Ob + l * DIN, Xin, Y, P_CTX, DIN, DFF, 0, 0, 0, 0, 0, 0);
        // BatchNorm (training-mode stats) in place on Y; bf16 copy -> XB
        zero_f32<<<8, 256, 0, stream>>>(ST, 2048);
        bn_stats<<<P_CTX / 64, 256, 0, stream>>>(Y, ST);
        bn_final<<<4, 256, 0, stream>>>(ST, gamma + l * DIN, beta + l * DIN);
        bn_apply_b<<<(P_CTX * DIN / 4) / 256, 256, 0, stream>>>(Y, XB, ST);
        float* t = Xin;
        Xin = Y;
        Y = t;
    }

    // temporal pool: split-K GEMM over 27 taps (A rows gathered from XB)
    wb_conv<<<(27 * DIN * DOUT) / 256, 256, 0, stream>>>(tpw, TWB);
    gemm_mfma<0, 0, 1><<<dim3(1, NPOS / 128, 27), 256, 0, stream>>>(
        XB, TWB, nullptr, nullptr, GP, NPOS, DOUT, DIN,
        (size_t)DIN / 8 * DOUT * 8, (size_t)NPOS * DOUT, 0, 0, 0, 0);
    conv3_reduce<<<(NPOS * DOUT) / 256, 256, 0, stream>>>(GP, tpb, R);
    goal_reduce<<<8, 128, 0, stream>>>(R, out);

    // frame upsample path (bf16 activations throughout)
    transpose_cm_pm<0><<<dim3(HWP / 16, DIN / 64, NF), dim3(16, 16), 0, stream>>>(
        frame, nullptr, F0B, DIN, HWP);
    wb_convT<<<(4 * DIN * DFF) / 256, 256, 0, stream>>>(u1w, W1B, DFF, DIN);
    wb_convT<<<(4 * DFF * DOUT) / 256, 256, 0, stream>>>(u2w, W2B, DOUT, DFF);
    // up1: relu(convT1), 4 quadrants via blockIdx.z, bf16 out with row remap
    gemm_mfma<11, 1, 0><<<dim3(DFF / 128, P_FRM / 128, 4), 256, 0, stream>>>(
        F0B, W1B, u1b, nullptr, HP1B, P_FRM, DFF, DIN,
        (size_t)DIN / 8 * DFF * 8, 0, 12, 144, 24, 576);
    // up2: convT2 (no relu), f32 out with row remap -> HP2
    gemm_mfma<1, 1, 0><<<dim3(DOUT / 128, P_H1 / 128, 4), 256, 0, stream>>>(
        HP1B, W2B, u2b, nullptr, HP2, P_H1, DOUT, DFF,
        (size_t)DFF / 8 * DOUT * 8, 0, 24, 576, 48, 2304);

    // final goal/state attention
    attn_logits<<<dim3(S2 / 16, NF), 256, 0, stream>>>(HP2, out, SG);
    attn_softmax<<<NF, 256, 0, stream>>>(SG);
    attn_pv<<<dim3(18, NF), 256, 0, stream>>>(HP2, SG, PP);
    attn_pv_reduce<<<NF, 128, 0, stream>>>(PP, out);
}